// Round 2
// baseline (254.565 us; speedup 1.0000x reference)
//
#include <hip/hip_runtime.h>

// ---------------------------------------------------------------------------
// TemporalHyperedge: loss[b] = 0.2 * sum_n ||cur[b]@r_proj - W@pre[b]||_2
//                              + sum_n (max_m W[n,m] + 0.001*||W[n,:]||_2)
// W = incidence_m masked to > 0.01. Output = [loss(32) , incidence_m(2048^2)].
//
// R6 change: (1) gemm_diff re-tiled for occupancy. R4/R5 were register-pinned
// at 2 waves/SIMD by the 128-AGPR accumulator (8192-elem wave tile) ->
// MfmaUtil ~30% regardless of schedule. Now: 1024 threads = 16 waves (4x4),
// wave tile 64x64 (64 acc regs, total <=128/wave) -> 4 waves/SIMD. Minimal
// counted pipeline: one s_barrier + one vmcnt(0)-with-slack per K-tile,
// stage(t+1) issued early so DMA hides under the ks-loop.
// (2) prep_all split into prep_inc + prep_tr so rocprof attributes the
// ~143us currently invisible outside gemm.
// ---------------------------------------------------------------------------

typedef __attribute__((ext_vector_type(8))) short bf16x8;
typedef __attribute__((ext_vector_type(8))) unsigned short ushort8;
typedef __attribute__((ext_vector_type(16))) float f32x16;

__device__ __forceinline__ unsigned short f2bf(float f) {
    union { float f; unsigned u; } x; x.f = f;
    unsigned r = x.u + 0x7fffu + ((x.u >> 16) & 1u);   // RNE
    return (unsigned short)(r >> 16);
}

#define GLL16(g, l)                                                         \
    __builtin_amdgcn_global_load_lds(                                       \
        (const __attribute__((address_space(1))) void*)(g),                 \
        (__attribute__((address_space(3))) void*)(l), 16, 0, 0)

// --------------------------------------------------------------------------
// transpose_64x64: src f32 (R,C) tile (r0,c0) -> dst bf16 (C,R).
// --------------------------------------------------------------------------
__device__ __forceinline__ void transpose_64x64(
    const float* __restrict__ src, unsigned short* __restrict__ dst,
    int R, int C, int r0, int c0, unsigned short* __restrict__ tile) {
    const int t = threadIdx.x;
    const int fr = t >> 4, fc = (t & 15) * 4;
#pragma unroll
    for (int it = 0; it < 4; ++it) {
        int m = fr + it * 16;
        float4 v = *(const float4*)(src + (size_t)(r0 + m) * C + c0 + fc);
        tile[(fc + 0) * 68 + m] = f2bf(v.x);
        tile[(fc + 1) * 68 + m] = f2bf(v.y);
        tile[(fc + 2) * 68 + m] = f2bf(v.z);
        tile[(fc + 3) * 68 + m] = f2bf(v.w);
    }
    __syncthreads();
    const int d = t >> 2, m0 = (t & 3) * 16;
    unsigned short v[16];
#pragma unroll
    for (int j = 0; j < 4; ++j)
        *(ushort4*)(v + j * 4) = *(const ushort4*)(tile + d * 68 + m0 + j * 4);
    unsigned short* dp = dst + (size_t)(c0 + d) * R + r0 + m0;
    ushort8 p0, p1;
#pragma unroll
    for (int j = 0; j < 8; ++j) { p0[j] = v[j]; p1[j] = v[8 + j]; }
    *(ushort8*)(dp) = p0;
    *(ushort8*)(dp + 8) = p1;
}

// --------------------------------------------------------------------------
// prep_inc: incidence rows: copy-out, -masked bf16 W, crow[row]=l1+1e-3*l2
// --------------------------------------------------------------------------
__global__ __launch_bounds__(256) void prep_inc(
    const float* __restrict__ inc, float* __restrict__ out_inc,
    unsigned short* __restrict__ Wneg, float* __restrict__ crow) {
    __shared__ float smax[4], ssum[4];
    const int row = blockIdx.x;
    const int t = threadIdx.x;
    const float4* src = (const float4*)(inc + (size_t)row * 2048);
    float4* dst = (float4*)(out_inc + (size_t)row * 2048);
    ushort4* wp = (ushort4*)(Wneg + (size_t)row * 2048);
    float lmax = 0.f, ss = 0.f;
#pragma unroll
    for (int it = 0; it < 2; ++it) {
        int i = it * 256 + t;
        float4 v = src[i];
        dst[i] = v;
        float w0 = v.x > 0.01f ? v.x : 0.f;
        float w1 = v.y > 0.01f ? v.y : 0.f;
        float w2 = v.z > 0.01f ? v.z : 0.f;
        float w3 = v.w > 0.01f ? v.w : 0.f;
        ushort4 p;
        p.x = f2bf(-w0); p.y = f2bf(-w1); p.z = f2bf(-w2); p.w = f2bf(-w3);
        wp[i] = p;
        lmax = fmaxf(lmax, fmaxf(fmaxf(w0, w1), fmaxf(w2, w3)));
        ss += w0 * w0 + w1 * w1 + w2 * w2 + w3 * w3;
    }
#pragma unroll
    for (int off = 32; off; off >>= 1) {
        lmax = fmaxf(lmax, __shfl_down(lmax, off));
        ss += __shfl_down(ss, off);
    }
    int wv = t >> 6, ln = t & 63;
    if (ln == 0) { smax[wv] = lmax; ssum[wv] = ss; }
    __syncthreads();
    if (t == 0) {
        float m = fmaxf(fmaxf(smax[0], smax[1]), fmaxf(smax[2], smax[3]));
        float s = ssum[0] + ssum[1] + ssum[2] + ssum[3];
        crow[row] = m + 0.001f * sqrtf(s);
    }
}

// --------------------------------------------------------------------------
// prep_tr: [0,4096) pre (32,2048,256) -> preT (32,256,2048) bf16 transpose
//          [4096,4112) r_proj (256,256) -> rprojT bf16 transpose
// --------------------------------------------------------------------------
__global__ __launch_bounds__(256) void prep_tr(
    const float* __restrict__ pre, unsigned short* __restrict__ preT,
    const float* __restrict__ r_proj, unsigned short* __restrict__ rprojT) {
    __shared__ unsigned short tile[64 * 68];
    const int bid = blockIdx.x;
    if (bid < 4096) {
        const int b = bid >> 7;
        const int mt = (bid & 127) >> 2;
        const int dt = bid & 3;
        transpose_64x64(pre + (size_t)b * 524288, preT + (size_t)b * 524288,
                        2048, 256, mt * 64, dt * 64, tile);
    } else {
        const int tt = bid - 4096;
        transpose_64x64(r_proj, rprojT, 256, 256, (tt >> 2) * 64, (tt & 3) * 64,
                        tile);
    }
}

// --------------------------------------------------------------------------
// gemm_diff: block = 256n x 256d, BK=64, K=2304. 32x32x16 MFMA.
// 16 waves (4m x 4n), per-wave C = 64x64 -> acc f32x16[2][2] = 64 AGPRs,
// total regs <= 128/wave -> 4 waves/SIMD (2x R5 occupancy).
// LDS: double-buffered A(32KB)+B(32KB) x2 = 128KB + ssq. Chunk-swizzled
// (LDS[r][p] = G[r][p ^ (r&7)], p = 16B chunk idx).
//
// Per K-tile t: vmcnt(0) [tile t landed, ~1 ks-loop of slack]; s_barrier
// [all waves' DMA visible + tile t-1 reads retired]; issue stage(t+1) into
// buf[c^1] (4 GLL16/wave, overlaps ks-loop); ks-loop (16 ds_read_b128 +
// 16 MFMA per wave). One barrier + one wait per K-tile.
// Tail: tiles 32..35, A from cur f32 (convert + swizzled ds_write), B from
// rprojT via GLL, __syncthreads-based.
// --------------------------------------------------------------------------
__global__ __launch_bounds__(1024) void gemm_diff(
    const unsigned short* __restrict__ Wneg,    // (2048,2048) bf16 neg+masked
    const float* __restrict__ cur,              // (32,2048,256) f32
    const unsigned short* __restrict__ preT,    // (32,256,2048) bf16
    const unsigned short* __restrict__ rprojT,  // (256,256) bf16
    float* __restrict__ Ssq)                    // (32,2048)
{
    const int n0 = blockIdx.x * 256;
    const int b  = blockIdx.y;

    __shared__ unsigned short Al[2 * 256 * 64];  // 64 KB
    __shared__ unsigned short Bl[2 * 256 * 64];  // 64 KB
    __shared__ float ssq[256];

    const int tid  = threadIdx.x;
    const int w    = tid >> 6;                   // 0..15
    const int lane = tid & 63;
    const int l32  = lane & 31;
    const int half = lane >> 5;
    const int wm   = w >> 2;                     // 0..3  (n-band of 64)
    const int wn   = w & 3;                      // 0..3  (d-band of 64)
    const int w8   = w * 8;
    const int grow  = lane >> 3;                 // row-within-8 for staging
    const int gbyte = ((lane & 7) ^ grow) * 16;  // swizzled source chunk
    const int sw    = (l32 & 7) * 8;             // fragment-read swizzle base

    if (tid < 256) ssq[tid] = 0.f;

    f32x16 acc[2][2] = {};

    const float*          curB = cur  + (size_t)b * 2048 * 256;
    const unsigned short* preB = preT + (size_t)b * 256 * 2048;
    const unsigned short* An   = Wneg + (size_t)n0 * 2048;

    // stage K-tile (A 256x64 + B 256x64) : 2+2 GLL16 per wave
#define STAGE_TILE(AP, BP, K0)                                                 \
    {                                                                          \
        _Pragma("unroll") for (int pass = 0; pass < 2; ++pass) {               \
            const int rowb = pass * 128 + w8;                                  \
            GLL16((const char*)(An + (size_t)(rowb + grow) * 2048 + (K0)) + gbyte, \
                  (char*)(AP) + rowb * 128);                                   \
        }                                                                      \
        _Pragma("unroll") for (int pass = 0; pass < 2; ++pass) {               \
            const int rowb = pass * 128 + w8;                                  \
            GLL16((const char*)(preB + (size_t)(rowb + grow) * 2048 + (K0)) + gbyte, \
                  (char*)(BP) + rowb * 128);                                   \
        }                                                                      \
    }

#define KS_LOOP(Ac, Bc)                                                        \
    _Pragma("unroll") for (int ks = 0; ks < 4; ++ks) {                         \
        const int ck = (ks * 2 + half) * 8;                                    \
        bf16x8 af[2], bfr[2];                                                  \
        _Pragma("unroll") for (int mi = 0; mi < 2; ++mi)                       \
            af[mi] = *(const bf16x8*)((Ac) + (wm * 64 + mi * 32 + l32) * 64 +  \
                                      (ck ^ sw));                              \
        _Pragma("unroll") for (int ni = 0; ni < 2; ++ni)                       \
            bfr[ni] = *(const bf16x8*)((Bc) + (wn * 64 + ni * 32 + l32) * 64 + \
                                       (ck ^ sw));                             \
        _Pragma("unroll") for (int mi = 0; mi < 2; ++mi)                       \
        _Pragma("unroll") for (int ni = 0; ni < 2; ++ni)                       \
            acc[mi][ni] = __builtin_amdgcn_mfma_f32_32x32x16_bf16(             \
                af[mi], bfr[ni], acc[mi][ni], 0, 0, 0);                        \
    }

    // ---- prologue: tile 0 -> buf0
    STAGE_TILE(Al, Bl, 0);

    // ---- main loop: tiles 0..31 (Wneg / preT)
    for (int t = 0; t < 32; ++t) {
        unsigned short* Ac = Al + (t & 1) * 16384;
        unsigned short* Bc = Bl + (t & 1) * 16384;
        unsigned short* Anx = Al + ((t & 1) ^ 1) * 16384;
        unsigned short* Bnx = Bl + ((t & 1) ^ 1) * 16384;

        asm volatile("s_waitcnt vmcnt(0)" ::: "memory");  // tile t landed (own)
        asm volatile("s_barrier" ::: "memory");           // all waves' DMA + WAR
        if (t < 31) { STAGE_TILE(Anx, Bnx, (t + 1) * 64); }
        KS_LOOP(Ac, Bc)
    }

    // ---- tail: tiles 32..35, A from cur f32, B from rprojT. buf0 only.
    for (int kt = 32; kt < 36; ++kt) {
        __syncthreads();
        const int kk = (kt - 32) * 64;
        const int row = tid >> 2;
        const int q   = tid & 3;
#pragma unroll
        for (int i = 0; i < 4; ++i) {
            const int k4 = q * 4 + i;
            float4 v = *(const float4*)(curB + (size_t)(n0 + row) * 256 + kk + k4 * 4);
            ushort4 p;
            p.x = f2bf(v.x); p.y = f2bf(v.y); p.z = f2bf(v.z); p.w = f2bf(v.w);
            const int pos = ((k4 >> 1) ^ (row & 7)) * 8 + (k4 & 1) * 4;
            *(ushort4*)(Al + row * 64 + pos) = p;
        }
#pragma unroll
        for (int pass = 0; pass < 2; ++pass) {
            const int rowb = pass * 128 + w8;
            GLL16((const char*)(rprojT + (size_t)(rowb + grow) * 256 + kk) + gbyte,
                  (char*)Bl + rowb * 128);
        }
        __syncthreads();
        KS_LOOP(Al, Bl)
    }
    __syncthreads();

    // 32x32 C/D layout: col(d)=lane&31, row(n)=(reg&3)+8*(reg>>2)+4*half
#pragma unroll
    for (int mi = 0; mi < 2; ++mi)
#pragma unroll
        for (int reg = 0; reg < 16; ++reg) {
            float s = 0.f;
#pragma unroll
            for (int ni = 0; ni < 2; ++ni) {
                float v = acc[mi][ni][reg];
                s += v * v;
            }
            s += __shfl_xor(s, 1);
            s += __shfl_xor(s, 2);
            s += __shfl_xor(s, 4);
            s += __shfl_xor(s, 8);
            s += __shfl_xor(s, 16);
            if (l32 == 0) {
                const int row = wm * 64 + mi * 32 +
                                (reg & 3) + 8 * (reg >> 2) + 4 * half;
                atomicAdd(&ssq[row], s);  // 4-way (wn)
            }
        }
    __syncthreads();
    if (tid < 256)
        Ssq[(size_t)b * 2048 + n0 + tid] = sqrtf(ssq[tid]);
}

// --------------------------------------------------------------------------
// finalize: loss[b] = 0.2 * sum_n Ssq[b,n] + sum_n crow[n]
// --------------------------------------------------------------------------
__global__ void finalize(const float* __restrict__ Ssq,
                         const float* __restrict__ crow,
                         float* __restrict__ out) {
    const int b = blockIdx.x;
    float s1 = 0.f, s2 = 0.f;
    for (int i = threadIdx.x; i < 2048; i += 256) {
        s1 += Ssq[(size_t)b * 2048 + i];
        s2 += crow[i];
    }
#pragma unroll
    for (int off = 32; off; off >>= 1) {
        s1 += __shfl_down(s1, off);
        s2 += __shfl_down(s2, off);
    }
    __shared__ float sm1[4], sm2[4];
    int wv = threadIdx.x >> 6, ln = threadIdx.x & 63;
    if (ln == 0) { sm1[wv] = s1; sm2[wv] = s2; }
    __syncthreads();
    if (threadIdx.x == 0)
        out[b] = 0.2f * (sm1[0] + sm1[1] + sm1[2] + sm1[3])
               + (sm2[0] + sm2[1] + sm2[2] + sm2[3]);
}

// --------------------------------------------------------------------------
extern "C" void kernel_launch(void* const* d_in, const int* in_sizes, int n_in,
                              void* d_out, int out_size, void* d_ws, size_t ws_size,
                              hipStream_t stream) {
    const float* cur    = (const float*)d_in[0];  // (32,2048,256)
    const float* pre    = (const float*)d_in[1];  // (32,2048,256)
    const float* r_proj = (const float*)d_in[2];  // (256,256)
    const float* inc    = (const float*)d_in[3];  // (2048,2048)
    float* out = (float*)d_out;                   // [0..31]=loss, [32..]=incidence

    char* ws = (char*)d_ws;
    unsigned short* Wneg   = (unsigned short*)(ws + 0);          //  8 MB
    unsigned short* preT   = (unsigned short*)(ws + 8388608);    // 32 MB
    unsigned short* rprojT = (unsigned short*)(ws + 41943040);   // 128 KB
    float*          Sbuf   = (float*)(ws + 42074112);            // 256 KB
    float*          crow   = (float*)(ws + 42336256);            // 8 KB

    prep_inc<<<2048, 256, 0, stream>>>(inc, out + 32, Wneg, crow);
    prep_tr<<<4112, 256, 0, stream>>>(pre, preT, r_proj, rprojT);
    gemm_diff<<<dim3(8, 32), 1024, 0, stream>>>(Wneg, cur, preT, rprojT, Sbuf);
    finalize<<<32, 256, 0, stream>>>(Sbuf, crow, out);
}